// Round 11
// baseline (369.869 us; speedup 1.0000x reference)
//
#include <hip/hip_runtime.h>

constexpr int N_NODES = 100000;
constexpr int N_EDGES = 1600000;
constexpr int IN_DIM  = 128;
constexpr int HID     = 64;
constexpr int C2      = 8;
constexpr int GDIM    = 24;
constexpr int NG      = 64;
constexpr float SLOPE = 0.01f;
constexpr int NB_SCAN = (N_NODES + 255) / 256;          // 391
constexpr int RANK_BLOCKS  = (N_EDGES / 4 + 255) / 256; // 1563
constexpr int GEMM_BLOCKS  = N_NODES / 16;              // 6250 (16 nodes/block, 4/wave)
constexpr int PLACE_BLOCKS = RANK_BLOCKS;               // 1563
constexpr int SCALE_BLOCKS = N_NODES * HID / 8 / 256;   // 3125 (8 bf16/thread)
constexpr int NINFO_BLOCKS = NB_SCAN;                   // 391

__device__ __forceinline__ float lrelu(float v) { return v > 0.f ? v : SLOPE * v; }

__device__ __forceinline__ float bflo(unsigned int u) { return __uint_as_float(u << 16); }
__device__ __forceinline__ float bfhi(unsigned int u) { return __uint_as_float(u & 0xffff0000u); }
__device__ __forceinline__ unsigned int f2bf_u(float f) {
    unsigned int i = __float_as_uint(f);
    return (i + 0x7fffu + ((i >> 16) & 1u)) >> 16;   // RNE, low 16 bits valid
}

// ---- fused front (NO LDS): rank blocks ∥ register-shfl gemm1 blocks ----
__global__ __launch_bounds__(256) void k_front(const float* __restrict__ x,
                                               const float* __restrict__ W1,
                                               const int* __restrict__ dst,
                                               int* __restrict__ deg,
                                               int* __restrict__ rnk,
                                               unsigned short* __restrict__ hs1) {
    if (blockIdx.x < RANK_BLOCKS) {
        int t = blockIdx.x * 256 + threadIdx.x;
        if (t < N_EDGES / 4) {
            int4 d = ((const int4*)dst)[t];
            int4 r;
            r.x = atomicAdd(&deg[d.x], 1);
            r.y = atomicAdd(&deg[d.y], 1);
            r.z = atomicAdd(&deg[d.z], 1);
            r.w = atomicAdd(&deg[d.w], 1);
            ((int4*)rnk)[t] = r;
        }
        return;
    }
    // gemm: wave handles 4 nodes; lane = output column; x in regs, shfl-broadcast
    int node0 = (blockIdx.x - RANK_BLOCKS) * 16 + (threadIdx.x >> 6) * 4;
    int lane  = threadIdx.x & 63;
    const float* xb = x + (size_t)node0 * IN_DIM + 2 * lane;
    float2 x0 = *(const float2*)(xb);
    float2 x1 = *(const float2*)(xb + IN_DIM);
    float2 x2 = *(const float2*)(xb + 2 * IN_DIM);
    float2 x3 = *(const float2*)(xb + 3 * IN_DIM);
    float a0 = 0.f, a1 = 0.f, a2 = 0.f, a3 = 0.f;
#pragma unroll 8
    for (int m = 0; m < 64; ++m) {
        float w0 = W1[(2 * m) * HID + lane];
        float w1 = W1[(2 * m + 1) * HID + lane];
        a0 += __shfl(x0.x, m) * w0 + __shfl(x0.y, m) * w1;
        a1 += __shfl(x1.x, m) * w0 + __shfl(x1.y, m) * w1;
        a2 += __shfl(x2.x, m) * w0 + __shfl(x2.y, m) * w1;
        a3 += __shfl(x3.x, m) * w0 + __shfl(x3.y, m) * w1;
    }
    hs1[(size_t)(node0 + 0) * HID + lane] = (unsigned short)f2bf_u(a0);
    hs1[(size_t)(node0 + 1) * HID + lane] = (unsigned short)f2bf_u(a1);
    hs1[(size_t)(node0 + 2) * HID + lane] = (unsigned short)f2bf_u(a2);
    hs1[(size_t)(node0 + 3) * HID + lane] = (unsigned short)f2bf_u(a3);
}

// ---- scan1: block-local exclusive scan of deg + dinv ----
__global__ void k_scan1(const int* __restrict__ deg, int* __restrict__ rowptr,
                        int* __restrict__ bsum, float* __restrict__ dinv) {
    __shared__ int s[256];
    int tid = threadIdx.x;
    int i = blockIdx.x * 256 + tid;
    int v = (i < N_NODES) ? deg[i] : 0;
    if (i < N_NODES) dinv[i] = rsqrtf((float)(v + 1));
    s[tid] = v;
    __syncthreads();
    for (int off = 1; off < 256; off <<= 1) {
        int t = (tid >= off) ? s[tid - off] : 0;
        __syncthreads();
        s[tid] += t;
        __syncthreads();
    }
    if (i < N_NODES) rowptr[i] = s[tid] - v;   // block-local exclusive
    if (tid == 255) bsum[blockIdx.x] = s[255];
}

// ---- scan2: exclusive scan of block sums ----
__global__ void k_scan2(const int* __restrict__ bsum, int* __restrict__ bsumx) {
    __shared__ int s[512];
    int tid = threadIdx.x;
    int v = (tid < NB_SCAN) ? bsum[tid] : 0;
    s[tid] = v;
    __syncthreads();
    for (int off = 1; off < 512; off <<= 1) {
        int t = (tid >= off) ? s[tid - off] : 0;
        __syncthreads();
        s[tid] += t;
        __syncthreads();
    }
    if (tid < NB_SCAN) bsumx[tid] = s[tid] - v;
}

// ---- fused mid (NO LDS): place ∥ in-place hs1 scale ∥ ninfo pack ----
__global__ __launch_bounds__(256) void k_mid(const int* __restrict__ src,
                                             const int* __restrict__ dst,
                                             const int* __restrict__ rnk,
                                             const int* __restrict__ rowptr,
                                             const int* __restrict__ bsumx,
                                             const int* __restrict__ deg,
                                             int* __restrict__ eidx,
                                             const float* __restrict__ dinv,
                                             unsigned short* __restrict__ hs1,
                                             int2* __restrict__ ninfo) {
    if (blockIdx.x < PLACE_BLOCKS) {
        int t = blockIdx.x * 256 + threadIdx.x;
        if (t < N_EDGES / 4) {
            int4 d = ((const int4*)dst)[t];
            int4 r = ((const int4*)rnk)[t];
            int4 s = ((const int4*)src)[t];
            int px = rowptr[d.x] + bsumx[d.x >> 8] + r.x;
            int py = rowptr[d.y] + bsumx[d.y >> 8] + r.y;
            int pz = rowptr[d.z] + bsumx[d.z >> 8] + r.z;
            int pw = rowptr[d.w] + bsumx[d.w >> 8] + r.w;
            eidx[px] = s.x; eidx[py] = s.y; eidx[pz] = s.z; eidx[pw] = s.w;
        }
        return;
    }
    if (blockIdx.x < PLACE_BLOCKS + SCALE_BLOCKS) {
        int t = (blockIdx.x - PLACE_BLOCKS) * 256 + threadIdx.x;   // < 800000 exactly
        int node = t >> 3;                     // 8 bf16 per thread
        float di = dinv[node];
        uint4 v = ((const uint4*)hs1)[t];
        uint4 o;
        o.x = f2bf_u(bflo(v.x) * di) | (f2bf_u(bfhi(v.x) * di) << 16);
        o.y = f2bf_u(bflo(v.y) * di) | (f2bf_u(bfhi(v.y) * di) << 16);
        o.z = f2bf_u(bflo(v.z) * di) | (f2bf_u(bfhi(v.z) * di) << 16);
        o.w = f2bf_u(bflo(v.w) * di) | (f2bf_u(bfhi(v.w) * di) << 16);
        ((uint4*)hs1)[t] = o;
        return;
    }
    int i = (blockIdx.x - PLACE_BLOCKS - SCALE_BLOCKS) * 256 + threadIdx.x;
    if (i < N_NODES) ninfo[i] = make_int2(rowptr[i] + bsumx[i >> 8], deg[i]);
}

// ---- layer-1 aggregate + epilogue + fused layer-2 GEMM (R9 numerics, ninfo) ----
__global__ __launch_bounds__(256) void k_agg1(const int2* __restrict__ ninfo,
                                              const int* __restrict__ eidx,
                                              const unsigned short* __restrict__ hs1,
                                              const float* __restrict__ dinv,
                                              const float* __restrict__ b1,
                                              const float* __restrict__ W2,
                                              float* __restrict__ hs2) {
    int node = blockIdx.x * 4 + (threadIdx.x >> 6);   // 25000 * 4 == 100000
    int lane = threadIdx.x & 63;
    int q    = lane & 7;     // columns 8q..8q+7
    int slot = lane >> 3;    // 8 edge slots
    float w2f[8];
#pragma unroll
    for (int i = 0; i < 8; ++i) w2f[i] = W2[(8 * q + i) * C2 + slot];
    int2 ni = ninfo[node];
    int start = ni.x, cnt = ni.y;
    uint4 hv = ((const uint4*)(hs1 + (size_t)node * HID))[q];
    float acc[8] = {0.f, 0.f, 0.f, 0.f, 0.f, 0.f, 0.f, 0.f};
    for (int base = 0; base < cnt; base += 64) {
        int idx = (base + lane < cnt) ? eidx[start + base + lane] : 0;
        int lim = min(64, cnt - base);       // uniform across wave
        int trips = (lim + 15) >> 4;         // uniform: 1..4
        for (int t = 0; t < trips; ++t) {
            int k0 = slot + t * 16;
            int k1 = k0 + 8;
            int s0 = __shfl(idx, k0);
            int s1 = __shfl(idx, k1 & 63);
            uint4 v0 = ((const uint4*)(hs1 + (size_t)s0 * HID))[q];
            uint4 v1 = ((const uint4*)(hs1 + (size_t)s1 * HID))[q];
            if (k0 >= lim) { v0.x = 0; v0.y = 0; v0.z = 0; v0.w = 0; }
            if (k1 >= lim) { v1.x = 0; v1.y = 0; v1.z = 0; v1.w = 0; }
            acc[0] += bflo(v0.x); acc[1] += bfhi(v0.x);
            acc[2] += bflo(v0.y); acc[3] += bfhi(v0.y);
            acc[4] += bflo(v0.z); acc[5] += bfhi(v0.z);
            acc[6] += bflo(v0.w); acc[7] += bfhi(v0.w);
            acc[0] += bflo(v1.x); acc[1] += bfhi(v1.x);
            acc[2] += bflo(v1.y); acc[3] += bfhi(v1.y);
            acc[4] += bflo(v1.z); acc[5] += bfhi(v1.z);
            acc[6] += bflo(v1.w); acc[7] += bfhi(v1.w);
        }
    }
#pragma unroll
    for (int m = 8; m < 64; m <<= 1)
#pragma unroll
        for (int i = 0; i < 8; ++i) acc[i] += __shfl_xor(acc[i], m);
    float self[8] = {bflo(hv.x), bfhi(hv.x), bflo(hv.y), bfhi(hv.y),
                     bflo(hv.z), bfhi(hv.z), bflo(hv.w), bfhi(hv.w)};
    float di = dinv[node];
    float4 bb0 = ((const float4*)b1)[2 * q];
    float4 bb1 = ((const float4*)b1)[2 * q + 1];
    float bv[8] = {bb0.x, bb0.y, bb0.z, bb0.w, bb1.x, bb1.y, bb1.z, bb1.w};
    float p = 0.f;
#pragma unroll
    for (int i = 0; i < 8; ++i) {
        float y = lrelu(di * (acc[i] + self[i]) + bv[i]);
        p += y * w2f[i];
    }
#pragma unroll
    for (int m = 1; m < 8; m <<= 1) p += __shfl_xor(p, m);
    if (q == 0) hs2[(size_t)node * C2 + slot] = p * di;
}

// ---- layer-2 aggregate + epilogue (R9 numerics, ninfo) ----
__global__ __launch_bounds__(256) void k_agg2(const int2* __restrict__ ninfo,
                                              const int* __restrict__ eidx,
                                              const float* __restrict__ hs2,
                                              const float* __restrict__ dinv,
                                              const float* __restrict__ b2,
                                              float* __restrict__ y2) {
    int node = blockIdx.x * 4 + (threadIdx.x >> 6);
    int lane = threadIdx.x & 63;
    int q    = lane & 1;
    int slot = lane >> 1;    // 32 slots
    int2 ni = ninfo[node];
    int start = ni.x, cnt = ni.y;
    float4 acc = make_float4(0.f, 0.f, 0.f, 0.f);
    for (int base = 0; base < cnt; base += 64) {
        int idx = (base + lane < cnt) ? eidx[start + base + lane] : 0;
        int lim = min(64, cnt - base);       // uniform
        int s0 = __shfl(idx, slot);
        int s1 = __shfl(idx, slot + 32);
        float4 v0 = ((const float4*)(hs2 + (size_t)s0 * C2))[q];
        float4 v1 = ((const float4*)(hs2 + (size_t)s1 * C2))[q];
        if (slot >= lim)      { v0.x = 0.f; v0.y = 0.f; v0.z = 0.f; v0.w = 0.f; }
        if (slot + 32 >= lim) { v1.x = 0.f; v1.y = 0.f; v1.z = 0.f; v1.w = 0.f; }
        acc.x += v0.x + v1.x; acc.y += v0.y + v1.y;
        acc.z += v0.z + v1.z; acc.w += v0.w + v1.w;
    }
    for (int m = 2; m < 64; m <<= 1) {
        acc.x += __shfl_xor(acc.x, m); acc.y += __shfl_xor(acc.y, m);
        acc.z += __shfl_xor(acc.z, m); acc.w += __shfl_xor(acc.w, m);
    }
    if (slot == 0) {
        float4 h = ((const float4*)(hs2 + (size_t)node * C2))[q];
        float di = dinv[node];
        const float* bb = b2 + q * 4;
        float4 r;
        r.x = lrelu(di * (acc.x + h.x) + bb[0]);
        r.y = lrelu(di * (acc.y + h.y) + bb[1]);
        r.z = lrelu(di * (acc.z + h.z) + bb[2]);
        r.w = lrelu(di * (acc.w + h.w) + bb[3]);
        ((float4*)(y2 + (size_t)node * C2))[q] = r;
    }
}

__device__ __forceinline__ int lower_bound(const int* __restrict__ b, int n, int v) {
    int lo = 0, hi = n;
    while (lo < hi) {
        int m = (lo + hi) >> 1;
        if (b[m] < v) lo = m + 1; else hi = m;
    }
    return lo;
}

// ---- pool + MLP: one block per graph, zero atomics ----
__global__ __launch_bounds__(256) void k_pool(const float* __restrict__ y2,
                                              const int* __restrict__ batch,
                                              const float* __restrict__ gfeat,
                                              const float* __restrict__ fcW1,
                                              const float* __restrict__ fcb1,
                                              const float* __restrict__ fcW2,
                                              const float* __restrict__ fcb2,
                                              float* __restrict__ out) {
    __shared__ float s[256];
    int g   = blockIdx.x;
    int tid = threadIdx.x;
    int start = lower_bound(batch, N_NODES, g);
    int end   = lower_bound(batch, N_NODES, g + 1);
    int col = tid & 7;
    float local = 0.f;
    for (int n = start + (tid >> 3); n < end; n += 32)
        local += y2[(size_t)n * C2 + col];
    s[tid] = local;
    __syncthreads();
    for (int off = 128; off >= 8; off >>= 1) {
        if (tid < off) s[tid] += s[tid + off];
        __syncthreads();
    }
    if (tid == 0) {
        float cnt = fmaxf((float)(end - start), 1.f);
        float z[C2 + GDIM];
        for (int c = 0; c < C2; ++c) z[c] = s[c] / cnt;
        for (int c = 0; c < GDIM; ++c) z[C2 + c] = gfeat[g * GDIM + c];
        float acc2 = fcb2[0];
        for (int j = 0; j < 16; ++j) {
            float acc = fcb1[j];
            for (int c = 0; c < C2 + GDIM; ++c) acc += z[c] * fcW1[c * 16 + j];
            acc2 += lrelu(acc) * fcW2[j];
        }
        out[g] = lrelu(acc2);
    }
}

extern "C" void kernel_launch(void* const* d_in, const int* in_sizes, int n_in,
                              void* d_out, int out_size, void* d_ws, size_t ws_size,
                              hipStream_t stream) {
    const float* x     = (const float*)d_in[0];
    const int*   ei    = (const int*)d_in[1];
    const int*   batch = (const int*)d_in[2];
    const float* gfeat = (const float*)d_in[3];
    const float* W1    = (const float*)d_in[4];
    const float* b1    = (const float*)d_in[5];
    const float* W2    = (const float*)d_in[6];
    const float* b2    = (const float*)d_in[7];
    const float* fcW1  = (const float*)d_in[8];
    const float* fcb1  = (const float*)d_in[9];
    const float* fcW2  = (const float*)d_in[10];
    const float* fcb2  = (const float*)d_in[11];
    const int* src = ei;
    const int* dst = ei + N_EDGES;

    char* ws = (char*)d_ws;
    size_t off = 0;
    auto alloc = [&](size_t bytes) -> void* {
        void* p = ws + off;
        off = (off + bytes + 255) & ~(size_t)255;
        return p;
    };
    int*   deg    = (int*)  alloc((size_t)N_NODES * 4);
    float* dinv   = (float*)alloc((size_t)N_NODES * 4);
    int*   rowptr = (int*)  alloc((size_t)N_NODES * 4);
    int*   bsum   = (int*)  alloc(512 * 4);
    int*   bsumx  = (int*)  alloc(512 * 4);
    int*   rnk    = (int*)  alloc((size_t)N_EDGES * 4);
    int*   eidx   = (int*)  alloc((size_t)N_EDGES * 4);
    unsigned short* hs1 = (unsigned short*)alloc((size_t)N_NODES * HID * 2);
    int2*  ninfo  = (int2*) alloc((size_t)N_NODES * 8);
    float* hs2    = (float*)alloc((size_t)N_NODES * C2 * 4);
    float* y2     = (float*)alloc((size_t)N_NODES * C2 * 4);

    hipMemsetAsync(deg, 0, (size_t)N_NODES * 4, stream);

    k_front<<<RANK_BLOCKS + GEMM_BLOCKS, 256, 0, stream>>>(x, W1, dst, deg, rnk, hs1);
    k_scan1<<<NB_SCAN, 256, 0, stream>>>(deg, rowptr, bsum, dinv);
    k_scan2<<<1, 512, 0, stream>>>(bsum, bsumx);
    k_mid  <<<PLACE_BLOCKS + SCALE_BLOCKS + NINFO_BLOCKS, 256, 0, stream>>>(
            src, dst, rnk, rowptr, bsumx, deg, eidx, dinv, hs1, ninfo);
    k_agg1 <<<N_NODES / 4, 256, 0, stream>>>(ninfo, eidx, hs1, dinv, b1, W2, hs2);
    k_agg2 <<<N_NODES / 4, 256, 0, stream>>>(ninfo, eidx, hs2, dinv, b2, y2);
    k_pool <<<NG, 256, 0, stream>>>(y2, batch, gfeat, fcW1, fcb1, fcW2, fcb2, (float*)d_out);
}

// Round 12
// 261.484 us; speedup vs baseline: 1.4145x; 1.4145x over previous
//
#include <hip/hip_runtime.h>

constexpr int N_NODES = 100000;
constexpr int N_EDGES = 1600000;
constexpr int IN_DIM  = 128;
constexpr int HID     = 64;
constexpr int C2      = 8;
constexpr int GDIM    = 24;
constexpr int NG      = 64;
constexpr float SLOPE = 0.01f;
constexpr int NB_SCAN = (N_NODES + 255) / 256;   // 391

__device__ __forceinline__ float lrelu(float v) { return v > 0.f ? v : SLOPE * v; }

__device__ __forceinline__ float bflo(unsigned int u) { return __uint_as_float(u << 16); }
__device__ __forceinline__ float bfhi(unsigned int u) { return __uint_as_float(u & 0xffff0000u); }
__device__ __forceinline__ unsigned short f2bf(float f) {
    unsigned int i = __float_as_uint(f);
    unsigned int r = (i + 0x7fffu + ((i >> 16) & 1u)) >> 16;   // RNE
    return (unsigned short)r;
}

// ---- rank pass: 4 edges/thread, vectorized ----
__global__ void k_rank(const int* __restrict__ dst, int* __restrict__ deg,
                       int* __restrict__ rnk) {
    int t = blockIdx.x * 256 + threadIdx.x;
    if (t < N_EDGES / 4) {
        int4 d = ((const int4*)dst)[t];
        int4 r;
        r.x = atomicAdd(&deg[d.x], 1);
        r.y = atomicAdd(&deg[d.y], 1);
        r.z = atomicAdd(&deg[d.z], 1);
        r.w = atomicAdd(&deg[d.w], 1);
        ((int4*)rnk)[t] = r;
    }
}

// ---- scan1: block-local exclusive scan of deg + dinv ----
__global__ void k_scan1(const int* __restrict__ deg, int* __restrict__ rowptr,
                        int* __restrict__ bsum, float* __restrict__ dinv) {
    __shared__ int s[256];
    int tid = threadIdx.x;
    int i = blockIdx.x * 256 + tid;
    int v = (i < N_NODES) ? deg[i] : 0;
    if (i < N_NODES) dinv[i] = rsqrtf((float)(v + 1));
    s[tid] = v;
    __syncthreads();
    for (int off = 1; off < 256; off <<= 1) {
        int t = (tid >= off) ? s[tid - off] : 0;
        __syncthreads();
        s[tid] += t;
        __syncthreads();
    }
    if (i < N_NODES) rowptr[i] = s[tid] - v;   // block-local exclusive
    if (tid == 255) bsum[blockIdx.x] = s[255];
}

// ---- scan2: exclusive scan of block sums ----
__global__ void k_scan2(const int* __restrict__ bsum, int* __restrict__ bsumx) {
    __shared__ int s[512];
    int tid = threadIdx.x;
    int v = (tid < NB_SCAN) ? bsum[tid] : 0;
    s[tid] = v;
    __syncthreads();
    for (int off = 1; off < 512; off <<= 1) {
        int t = (tid >= off) ? s[tid - off] : 0;
        __syncthreads();
        s[tid] += t;
        __syncthreads();
    }
    if (tid < NB_SCAN) bsumx[tid] = s[tid] - v;
}

// ---- place: 4 edges/thread, atomic-free scatter ----
__global__ void k_place(const int* __restrict__ src, const int* __restrict__ dst,
                        const int* __restrict__ rnk, const int* __restrict__ rowptr,
                        const int* __restrict__ bsumx, int* __restrict__ eidx) {
    int t = blockIdx.x * 256 + threadIdx.x;
    if (t < N_EDGES / 4) {
        int4 d = ((const int4*)dst)[t];
        int4 r = ((const int4*)rnk)[t];
        int4 s = ((const int4*)src)[t];
        int px = rowptr[d.x] + bsumx[d.x >> 8] + r.x;
        int py = rowptr[d.y] + bsumx[d.y >> 8] + r.y;
        int pz = rowptr[d.z] + bsumx[d.z >> 8] + r.z;
        int pw = rowptr[d.w] + bsumx[d.w >> 8] + r.w;
        eidx[px] = s.x; eidx[py] = s.y; eidx[pz] = s.z; eidx[pw] = s.w;
    }
}

// ---- layer-1 GEMM: hs1(bf16)[n,:] = (x[n,:] @ W1) * dinv[n] ----
__global__ __launch_bounds__(256) void k_gemm1(const float* __restrict__ x,
                                               const float* __restrict__ W1,
                                               const float* __restrict__ dinv,
                                               unsigned short* __restrict__ hs1) {
    __shared__ float sW[IN_DIM * HID];   // 32 KiB
    __shared__ float sX[32][IN_DIM];     // 16 KiB
    int node0 = blockIdx.x * 32;         // 3125 * 32 == 100000
    for (int t = threadIdx.x; t < IN_DIM * HID / 4; t += 256)
        ((float4*)sW)[t] = ((const float4*)W1)[t];
    for (int t = threadIdx.x; t < 32 * IN_DIM / 4; t += 256) {
        int r = t >> 5, c4 = t & 31;
        ((float4*)&sX[r][0])[c4] = ((const float4*)(x + (size_t)(node0 + r) * IN_DIM))[c4];
    }
    __syncthreads();
    int col = threadIdx.x & 63;
    int nb  = (threadIdx.x >> 6) * 8;
    float acc[8] = {0.f, 0.f, 0.f, 0.f, 0.f, 0.f, 0.f, 0.f};
    for (int k4 = 0; k4 < IN_DIM; k4 += 4) {
        float w0 = sW[(k4 + 0) * HID + col];
        float w1 = sW[(k4 + 1) * HID + col];
        float w2 = sW[(k4 + 2) * HID + col];
        float w3 = sW[(k4 + 3) * HID + col];
#pragma unroll
        for (int j = 0; j < 8; ++j) {
            float4 xv = *((const float4*)&sX[nb + j][k4]);
            acc[j] += xv.x * w0 + xv.y * w1 + xv.z * w2 + xv.w * w3;
        }
    }
#pragma unroll
    for (int j = 0; j < 8; ++j) {
        int n = node0 + nb + j;
        hs1[(size_t)n * HID + col] = f2bf(acc[j] * dinv[n]);
    }
}

// ---- layer-1 aggregate + epilogue + fused layer-2 GEMM ----
// R9 numerics; 4 nodes per wave sequentially (dispatch-rate amortization)
__global__ __launch_bounds__(256) void k_agg1(const int* __restrict__ rowptr,
                                              const int* __restrict__ bsumx,
                                              const int* __restrict__ deg,
                                              const int* __restrict__ eidx,
                                              const unsigned short* __restrict__ hs1,
                                              const float* __restrict__ dinv,
                                              const float* __restrict__ b1,
                                              const float* __restrict__ W2,
                                              float* __restrict__ hs2) {
    int lane = threadIdx.x & 63;
    int q    = lane & 7;     // columns 8q..8q+7
    int slot = lane >> 3;    // 8 edge slots
    float w2f[8];
#pragma unroll
    for (int i = 0; i < 8; ++i) w2f[i] = W2[(8 * q + i) * C2 + slot];
    float4 bb0 = ((const float4*)b1)[2 * q];
    float4 bb1 = ((const float4*)b1)[2 * q + 1];
    float bv[8] = {bb0.x, bb0.y, bb0.z, bb0.w, bb1.x, bb1.y, bb1.z, bb1.w};
    int node_base = blockIdx.x * 16 + (threadIdx.x >> 6) * 4;   // 6250 * 16 == 100000

    for (int nn = 0; nn < 4; ++nn) {
        int node  = node_base + nn;
        int start = rowptr[node] + bsumx[node >> 8];
        int cnt   = deg[node];
        uint4 hv = ((const uint4*)(hs1 + (size_t)node * HID))[q];
        float acc[8] = {0.f, 0.f, 0.f, 0.f, 0.f, 0.f, 0.f, 0.f};
        for (int base = 0; base < cnt; base += 64) {
            int idx = (base + lane < cnt) ? eidx[start + base + lane] : 0;
            int lim = min(64, cnt - base);       // uniform across wave
            int trips = (lim + 15) >> 4;         // uniform: 1..4
            for (int t = 0; t < trips; ++t) {
                int k0 = slot + t * 16;
                int k1 = k0 + 8;
                int s0 = __shfl(idx, k0);
                int s1 = __shfl(idx, k1 & 63);
                uint4 v0 = ((const uint4*)(hs1 + (size_t)s0 * HID))[q];
                uint4 v1 = ((const uint4*)(hs1 + (size_t)s1 * HID))[q];
                if (k0 >= lim) { v0.x = 0; v0.y = 0; v0.z = 0; v0.w = 0; }
                if (k1 >= lim) { v1.x = 0; v1.y = 0; v1.z = 0; v1.w = 0; }
                acc[0] += bflo(v0.x); acc[1] += bfhi(v0.x);
                acc[2] += bflo(v0.y); acc[3] += bfhi(v0.y);
                acc[4] += bflo(v0.z); acc[5] += bfhi(v0.z);
                acc[6] += bflo(v0.w); acc[7] += bfhi(v0.w);
                acc[0] += bflo(v1.x); acc[1] += bfhi(v1.x);
                acc[2] += bflo(v1.y); acc[3] += bfhi(v1.y);
                acc[4] += bflo(v1.z); acc[5] += bfhi(v1.z);
                acc[6] += bflo(v1.w); acc[7] += bfhi(v1.w);
            }
        }
#pragma unroll
        for (int m = 8; m < 64; m <<= 1)
#pragma unroll
            for (int i = 0; i < 8; ++i) acc[i] += __shfl_xor(acc[i], m);
        float self[8] = {bflo(hv.x), bfhi(hv.x), bflo(hv.y), bfhi(hv.y),
                         bflo(hv.z), bfhi(hv.z), bflo(hv.w), bfhi(hv.w)};
        float di = dinv[node];
        float p = 0.f;
#pragma unroll
        for (int i = 0; i < 8; ++i) {
            float y = lrelu(di * (acc[i] + self[i]) + bv[i]);
            p += y * w2f[i];
        }
#pragma unroll
        for (int m = 1; m < 8; m <<= 1) p += __shfl_xor(p, m);
        if (q == 0) hs2[(size_t)node * C2 + slot] = p * di;
    }
}

// ---- layer-2 aggregate + epilogue: R9 numerics; 4 nodes per wave ----
__global__ __launch_bounds__(256) void k_agg2(const int* __restrict__ rowptr,
                                              const int* __restrict__ bsumx,
                                              const int* __restrict__ deg,
                                              const int* __restrict__ eidx,
                                              const float* __restrict__ hs2,
                                              const float* __restrict__ dinv,
                                              const float* __restrict__ b2,
                                              float* __restrict__ y2) {
    int lane = threadIdx.x & 63;
    int q    = lane & 1;
    int slot = lane >> 1;    // 32 slots
    int node_base = blockIdx.x * 16 + (threadIdx.x >> 6) * 4;   // 6250 * 16 == 100000

    for (int nn = 0; nn < 4; ++nn) {
        int node  = node_base + nn;
        int start = rowptr[node] + bsumx[node >> 8];
        int cnt   = deg[node];
        float4 acc = make_float4(0.f, 0.f, 0.f, 0.f);
        for (int base = 0; base < cnt; base += 64) {
            int idx = (base + lane < cnt) ? eidx[start + base + lane] : 0;
            int lim = min(64, cnt - base);       // uniform
            int s0 = __shfl(idx, slot);
            int s1 = __shfl(idx, slot + 32);
            float4 v0 = ((const float4*)(hs2 + (size_t)s0 * C2))[q];
            float4 v1 = ((const float4*)(hs2 + (size_t)s1 * C2))[q];
            if (slot >= lim)      { v0.x = 0.f; v0.y = 0.f; v0.z = 0.f; v0.w = 0.f; }
            if (slot + 32 >= lim) { v1.x = 0.f; v1.y = 0.f; v1.z = 0.f; v1.w = 0.f; }
            acc.x += v0.x + v1.x; acc.y += v0.y + v1.y;
            acc.z += v0.z + v1.z; acc.w += v0.w + v1.w;
        }
        for (int m = 2; m < 64; m <<= 1) {
            acc.x += __shfl_xor(acc.x, m); acc.y += __shfl_xor(acc.y, m);
            acc.z += __shfl_xor(acc.z, m); acc.w += __shfl_xor(acc.w, m);
        }
        if (slot == 0) {
            float4 h = ((const float4*)(hs2 + (size_t)node * C2))[q];
            float di = dinv[node];
            const float* bb = b2 + q * 4;
            float4 r;
            r.x = lrelu(di * (acc.x + h.x) + bb[0]);
            r.y = lrelu(di * (acc.y + h.y) + bb[1]);
            r.z = lrelu(di * (acc.z + h.z) + bb[2]);
            r.w = lrelu(di * (acc.w + h.w) + bb[3]);
            ((float4*)(y2 + (size_t)node * C2))[q] = r;
        }
    }
}

__device__ __forceinline__ int lower_bound(const int* __restrict__ b, int n, int v) {
    int lo = 0, hi = n;
    while (lo < hi) {
        int m = (lo + hi) >> 1;
        if (b[m] < v) lo = m + 1; else hi = m;
    }
    return lo;
}

// ---- pool + MLP: one block per graph, zero atomics ----
__global__ __launch_bounds__(256) void k_pool(const float* __restrict__ y2,
                                              const int* __restrict__ batch,
                                              const float* __restrict__ gfeat,
                                              const float* __restrict__ fcW1,
                                              const float* __restrict__ fcb1,
                                              const float* __restrict__ fcW2,
                                              const float* __restrict__ fcb2,
                                              float* __restrict__ out) {
    __shared__ float s[256];
    int g   = blockIdx.x;
    int tid = threadIdx.x;
    int start = lower_bound(batch, N_NODES, g);
    int end   = lower_bound(batch, N_NODES, g + 1);
    int col = tid & 7;
    float local = 0.f;
    for (int n = start + (tid >> 3); n < end; n += 32)
        local += y2[(size_t)n * C2 + col];
    s[tid] = local;
    __syncthreads();
    for (int off = 128; off >= 8; off >>= 1) {
        if (tid < off) s[tid] += s[tid + off];
        __syncthreads();
    }
    if (tid == 0) {
        float cnt = fmaxf((float)(end - start), 1.f);
        float z[C2 + GDIM];
        for (int c = 0; c < C2; ++c) z[c] = s[c] / cnt;
        for (int c = 0; c < GDIM; ++c) z[C2 + c] = gfeat[g * GDIM + c];
        float acc2 = fcb2[0];
        for (int j = 0; j < 16; ++j) {
            float acc = fcb1[j];
            for (int c = 0; c < C2 + GDIM; ++c) acc += z[c] * fcW1[c * 16 + j];
            acc2 += lrelu(acc) * fcW2[j];
        }
        out[g] = lrelu(acc2);
    }
}

extern "C" void kernel_launch(void* const* d_in, const int* in_sizes, int n_in,
                              void* d_out, int out_size, void* d_ws, size_t ws_size,
                              hipStream_t stream) {
    const float* x     = (const float*)d_in[0];
    const int*   ei    = (const int*)d_in[1];
    const int*   batch = (const int*)d_in[2];
    const float* gfeat = (const float*)d_in[3];
    const float* W1    = (const float*)d_in[4];
    const float* b1    = (const float*)d_in[5];
    const float* W2    = (const float*)d_in[6];
    const float* b2    = (const float*)d_in[7];
    const float* fcW1  = (const float*)d_in[8];
    const float* fcb1  = (const float*)d_in[9];
    const float* fcW2  = (const float*)d_in[10];
    const float* fcb2  = (const float*)d_in[11];
    const int* src = ei;
    const int* dst = ei + N_EDGES;

    char* ws = (char*)d_ws;
    size_t off = 0;
    auto alloc = [&](size_t bytes) -> void* {
        void* p = ws + off;
        off = (off + bytes + 255) & ~(size_t)255;
        return p;
    };
    int*   deg    = (int*)  alloc((size_t)N_NODES * 4);
    float* dinv   = (float*)alloc((size_t)N_NODES * 4);
    int*   rowptr = (int*)  alloc((size_t)N_NODES * 4);
    int*   bsum   = (int*)  alloc(512 * 4);
    int*   bsumx  = (int*)  alloc(512 * 4);
    int*   rnk    = (int*)  alloc((size_t)N_EDGES * 4);
    int*   eidx   = (int*)  alloc((size_t)N_EDGES * 4);
    unsigned short* hs1 = (unsigned short*)alloc((size_t)N_NODES * HID * 2);
    float* hs2    = (float*)alloc((size_t)N_NODES * C2 * 4);
    float* y2     = (float*)alloc((size_t)N_NODES * C2 * 4);

    hipMemsetAsync(deg, 0, (size_t)N_NODES * 4, stream);

    k_rank <<<(N_EDGES / 4 + 255) / 256, 256, 0, stream>>>(dst, deg, rnk);
    k_scan1<<<NB_SCAN, 256, 0, stream>>>(deg, rowptr, bsum, dinv);
    k_scan2<<<1, 512, 0, stream>>>(bsum, bsumx);
    k_place<<<(N_EDGES / 4 + 255) / 256, 256, 0, stream>>>(src, dst, rnk, rowptr, bsumx, eidx);

    k_gemm1<<<N_NODES / 32, 256, 0, stream>>>(x, W1, dinv, hs1);
    k_agg1 <<<N_NODES / 16, 256, 0, stream>>>(rowptr, bsumx, deg, eidx, hs1, dinv, b1, W2, hs2);
    k_agg2 <<<N_NODES / 16, 256, 0, stream>>>(rowptr, bsumx, deg, eidx, hs2, dinv, b2, y2);
    k_pool <<<NG, 256, 0, stream>>>(y2, batch, gfeat, fcW1, fcb1, fcW2, fcb2, (float*)d_out);
}

// Round 13
// 260.756 us; speedup vs baseline: 1.4184x; 1.0028x over previous
//
#include <hip/hip_runtime.h>

constexpr int N_NODES = 100000;
constexpr int N_EDGES = 1600000;
constexpr int IN_DIM  = 128;
constexpr int HID     = 64;
constexpr int C2      = 8;
constexpr int GDIM    = 24;
constexpr int NG      = 64;
constexpr int NREP    = 8;                       // one histogram replica per XCD
constexpr float SLOPE = 0.01f;
constexpr int NB_SCAN = (N_NODES + 255) / 256;   // 391

__device__ __forceinline__ float lrelu(float v) { return v > 0.f ? v : SLOPE * v; }

__device__ __forceinline__ float bflo(unsigned int u) { return __uint_as_float(u << 16); }
__device__ __forceinline__ float bfhi(unsigned int u) { return __uint_as_float(u & 0xffff0000u); }
__device__ __forceinline__ unsigned short f2bf(float f) {
    unsigned int i = __float_as_uint(f);
    unsigned int r = (i + 0x7fffu + ((i >> 16) & 1u)) >> 16;   // RNE
    return (unsigned short)r;
}

// ---- rank pass: 4 edges/thread; atomics into XCD-local replica (blockIdx&7) ----
__global__ void k_rank(const int* __restrict__ dst, int* __restrict__ cnt,
                       int* __restrict__ rnk) {
    int t = blockIdx.x * 256 + threadIdx.x;
    int* c = cnt + (size_t)(blockIdx.x & (NREP - 1)) * N_NODES;
    if (t < N_EDGES / 4) {
        int4 d = ((const int4*)dst)[t];
        int4 r;
        r.x = atomicAdd(&c[d.x], 1);
        r.y = atomicAdd(&c[d.y], 1);
        r.z = atomicAdd(&c[d.z], 1);
        r.w = atomicAdd(&c[d.w], 1);
        ((int4*)rnk)[t] = r;
    }
}

// ---- scan1: total deg = sum of replicas; dinv; block-local exclusive scan ----
__global__ void k_scan1(const int* __restrict__ cnt, int* __restrict__ deg,
                        int* __restrict__ rowptr, int* __restrict__ bsum,
                        float* __restrict__ dinv) {
    __shared__ int s[256];
    int tid = threadIdx.x;
    int i = blockIdx.x * 256 + tid;
    int v = 0;
    if (i < N_NODES) {
#pragma unroll
        for (int r = 0; r < NREP; ++r) v += cnt[(size_t)r * N_NODES + i];
        deg[i] = v;
        dinv[i] = rsqrtf((float)(v + 1));
    }
    s[tid] = v;
    __syncthreads();
    for (int off = 1; off < 256; off <<= 1) {
        int t = (tid >= off) ? s[tid - off] : 0;
        __syncthreads();
        s[tid] += t;
        __syncthreads();
    }
    if (i < N_NODES) rowptr[i] = s[tid] - v;   // block-local exclusive
    if (tid == 255) bsum[blockIdx.x] = s[255];
}

// ---- scan2: exclusive scan of block sums ----
__global__ void k_scan2(const int* __restrict__ bsum, int* __restrict__ bsumx) {
    __shared__ int s[512];
    int tid = threadIdx.x;
    int v = (tid < NB_SCAN) ? bsum[tid] : 0;
    s[tid] = v;
    __syncthreads();
    for (int off = 1; off < 512; off <<= 1) {
        int t = (tid >= off) ? s[tid - off] : 0;
        __syncthreads();
        s[tid] += t;
        __syncthreads();
    }
    if (tid < NB_SCAN) bsumx[tid] = s[tid] - v;
}

// ---- ofs: overwrite cnt[r][i] with global slot base for (replica r, node i) ----
__global__ void k_ofs(int* __restrict__ cnt, const int* __restrict__ rowptr,
                      const int* __restrict__ bsumx) {
    int i = blockIdx.x * 256 + threadIdx.x;
    if (i < N_NODES) {
        int g = rowptr[i] + bsumx[i >> 8];
#pragma unroll
        for (int r = 0; r < NREP; ++r) {
            int c = cnt[(size_t)r * N_NODES + i];
            cnt[(size_t)r * N_NODES + i] = g;
            g += c;
        }
    }
}

// ---- place: 4 edges/thread; same block geometry as rank -> same replica ----
__global__ void k_place(const int* __restrict__ src, const int* __restrict__ dst,
                        const int* __restrict__ rnk, const int* __restrict__ cnt,
                        int* __restrict__ eidx) {
    int t = blockIdx.x * 256 + threadIdx.x;
    const int* ofs = cnt + (size_t)(blockIdx.x & (NREP - 1)) * N_NODES;
    if (t < N_EDGES / 4) {
        int4 d = ((const int4*)dst)[t];
        int4 r = ((const int4*)rnk)[t];
        int4 s = ((const int4*)src)[t];
        eidx[ofs[d.x] + r.x] = s.x;
        eidx[ofs[d.y] + r.y] = s.y;
        eidx[ofs[d.z] + r.z] = s.z;
        eidx[ofs[d.w] + r.w] = s.w;
    }
}

// ---- layer-1 GEMM: hs1(bf16)[n,:] = (x[n,:] @ W1) * dinv[n] ----
__global__ __launch_bounds__(256) void k_gemm1(const float* __restrict__ x,
                                               const float* __restrict__ W1,
                                               const float* __restrict__ dinv,
                                               unsigned short* __restrict__ hs1) {
    __shared__ float sW[IN_DIM * HID];   // 32 KiB
    __shared__ float sX[32][IN_DIM];     // 16 KiB
    int node0 = blockIdx.x * 32;         // 3125 * 32 == 100000
    for (int t = threadIdx.x; t < IN_DIM * HID / 4; t += 256)
        ((float4*)sW)[t] = ((const float4*)W1)[t];
    for (int t = threadIdx.x; t < 32 * IN_DIM / 4; t += 256) {
        int r = t >> 5, c4 = t & 31;
        ((float4*)&sX[r][0])[c4] = ((const float4*)(x + (size_t)(node0 + r) * IN_DIM))[c4];
    }
    __syncthreads();
    int col = threadIdx.x & 63;
    int nb  = (threadIdx.x >> 6) * 8;
    float acc[8] = {0.f, 0.f, 0.f, 0.f, 0.f, 0.f, 0.f, 0.f};
    for (int k4 = 0; k4 < IN_DIM; k4 += 4) {
        float w0 = sW[(k4 + 0) * HID + col];
        float w1 = sW[(k4 + 1) * HID + col];
        float w2 = sW[(k4 + 2) * HID + col];
        float w3 = sW[(k4 + 3) * HID + col];
#pragma unroll
        for (int j = 0; j < 8; ++j) {
            float4 xv = *((const float4*)&sX[nb + j][k4]);
            acc[j] += xv.x * w0 + xv.y * w1 + xv.z * w2 + xv.w * w3;
        }
    }
#pragma unroll
    for (int j = 0; j < 8; ++j) {
        int n = node0 + nb + j;
        hs1[(size_t)n * HID + col] = f2bf(acc[j] * dinv[n]);
    }
}

// ---- layer-1 aggregate + epilogue + fused layer-2 GEMM (R12, passed) ----
__global__ __launch_bounds__(256) void k_agg1(const int* __restrict__ rowptr,
                                              const int* __restrict__ bsumx,
                                              const int* __restrict__ deg,
                                              const int* __restrict__ eidx,
                                              const unsigned short* __restrict__ hs1,
                                              const float* __restrict__ dinv,
                                              const float* __restrict__ b1,
                                              const float* __restrict__ W2,
                                              float* __restrict__ hs2) {
    int lane = threadIdx.x & 63;
    int q    = lane & 7;     // columns 8q..8q+7
    int slot = lane >> 3;    // 8 edge slots
    float w2f[8];
#pragma unroll
    for (int i = 0; i < 8; ++i) w2f[i] = W2[(8 * q + i) * C2 + slot];
    float4 bb0 = ((const float4*)b1)[2 * q];
    float4 bb1 = ((const float4*)b1)[2 * q + 1];
    float bv[8] = {bb0.x, bb0.y, bb0.z, bb0.w, bb1.x, bb1.y, bb1.z, bb1.w};
    int node_base = blockIdx.x * 16 + (threadIdx.x >> 6) * 4;   // 6250 * 16 == 100000

    for (int nn = 0; nn < 4; ++nn) {
        int node  = node_base + nn;
        int start = rowptr[node] + bsumx[node >> 8];
        int cnt   = deg[node];
        uint4 hv = ((const uint4*)(hs1 + (size_t)node * HID))[q];
        float acc[8] = {0.f, 0.f, 0.f, 0.f, 0.f, 0.f, 0.f, 0.f};
        for (int base = 0; base < cnt; base += 64) {
            int idx = (base + lane < cnt) ? eidx[start + base + lane] : 0;
            int lim = min(64, cnt - base);       // uniform across wave
            int trips = (lim + 15) >> 4;         // uniform: 1..4
            for (int t = 0; t < trips; ++t) {
                int k0 = slot + t * 16;
                int k1 = k0 + 8;
                int s0 = __shfl(idx, k0);
                int s1 = __shfl(idx, k1 & 63);
                uint4 v0 = ((const uint4*)(hs1 + (size_t)s0 * HID))[q];
                uint4 v1 = ((const uint4*)(hs1 + (size_t)s1 * HID))[q];
                if (k0 >= lim) { v0.x = 0; v0.y = 0; v0.z = 0; v0.w = 0; }
                if (k1 >= lim) { v1.x = 0; v1.y = 0; v1.z = 0; v1.w = 0; }
                acc[0] += bflo(v0.x); acc[1] += bfhi(v0.x);
                acc[2] += bflo(v0.y); acc[3] += bfhi(v0.y);
                acc[4] += bflo(v0.z); acc[5] += bfhi(v0.z);
                acc[6] += bflo(v0.w); acc[7] += bfhi(v0.w);
                acc[0] += bflo(v1.x); acc[1] += bfhi(v1.x);
                acc[2] += bflo(v1.y); acc[3] += bfhi(v1.y);
                acc[4] += bflo(v1.z); acc[5] += bfhi(v1.z);
                acc[6] += bflo(v1.w); acc[7] += bfhi(v1.w);
            }
        }
#pragma unroll
        for (int m = 8; m < 64; m <<= 1)
#pragma unroll
            for (int i = 0; i < 8; ++i) acc[i] += __shfl_xor(acc[i], m);
        float self[8] = {bflo(hv.x), bfhi(hv.x), bflo(hv.y), bfhi(hv.y),
                         bflo(hv.z), bfhi(hv.z), bflo(hv.w), bfhi(hv.w)};
        float di = dinv[node];
        float p = 0.f;
#pragma unroll
        for (int i = 0; i < 8; ++i) {
            float y = lrelu(di * (acc[i] + self[i]) + bv[i]);
            p += y * w2f[i];
        }
#pragma unroll
        for (int m = 1; m < 8; m <<= 1) p += __shfl_xor(p, m);
        if (q == 0) hs2[(size_t)node * C2 + slot] = p * di;
    }
}

// ---- layer-2 aggregate + epilogue (R12, passed) ----
__global__ __launch_bounds__(256) void k_agg2(const int* __restrict__ rowptr,
                                              const int* __restrict__ bsumx,
                                              const int* __restrict__ deg,
                                              const int* __restrict__ eidx,
                                              const float* __restrict__ hs2,
                                              const float* __restrict__ dinv,
                                              const float* __restrict__ b2,
                                              float* __restrict__ y2) {
    int lane = threadIdx.x & 63;
    int q    = lane & 1;
    int slot = lane >> 1;    // 32 slots
    int node_base = blockIdx.x * 16 + (threadIdx.x >> 6) * 4;   // 6250 * 16 == 100000

    for (int nn = 0; nn < 4; ++nn) {
        int node  = node_base + nn;
        int start = rowptr[node] + bsumx[node >> 8];
        int cnt   = deg[node];
        float4 acc = make_float4(0.f, 0.f, 0.f, 0.f);
        for (int base = 0; base < cnt; base += 64) {
            int idx = (base + lane < cnt) ? eidx[start + base + lane] : 0;
            int lim = min(64, cnt - base);       // uniform
            int s0 = __shfl(idx, slot);
            int s1 = __shfl(idx, slot + 32);
            float4 v0 = ((const float4*)(hs2 + (size_t)s0 * C2))[q];
            float4 v1 = ((const float4*)(hs2 + (size_t)s1 * C2))[q];
            if (slot >= lim)      { v0.x = 0.f; v0.y = 0.f; v0.z = 0.f; v0.w = 0.f; }
            if (slot + 32 >= lim) { v1.x = 0.f; v1.y = 0.f; v1.z = 0.f; v1.w = 0.f; }
            acc.x += v0.x + v1.x; acc.y += v0.y + v1.y;
            acc.z += v0.z + v1.z; acc.w += v0.w + v1.w;
        }
        for (int m = 2; m < 64; m <<= 1) {
            acc.x += __shfl_xor(acc.x, m); acc.y += __shfl_xor(acc.y, m);
            acc.z += __shfl_xor(acc.z, m); acc.w += __shfl_xor(acc.w, m);
        }
        if (slot == 0) {
            float4 h = ((const float4*)(hs2 + (size_t)node * C2))[q];
            float di = dinv[node];
            const float* bb = b2 + q * 4;
            float4 r;
            r.x = lrelu(di * (acc.x + h.x) + bb[0]);
            r.y = lrelu(di * (acc.y + h.y) + bb[1]);
            r.z = lrelu(di * (acc.z + h.z) + bb[2]);
            r.w = lrelu(di * (acc.w + h.w) + bb[3]);
            ((float4*)(y2 + (size_t)node * C2))[q] = r;
        }
    }
}

__device__ __forceinline__ int lower_bound(const int* __restrict__ b, int n, int v) {
    int lo = 0, hi = n;
    while (lo < hi) {
        int m = (lo + hi) >> 1;
        if (b[m] < v) lo = m + 1; else hi = m;
    }
    return lo;
}

// ---- pool + MLP: one block per graph, zero atomics ----
__global__ __launch_bounds__(256) void k_pool(const float* __restrict__ y2,
                                              const int* __restrict__ batch,
                                              const float* __restrict__ gfeat,
                                              const float* __restrict__ fcW1,
                                              const float* __restrict__ fcb1,
                                              const float* __restrict__ fcW2,
                                              const float* __restrict__ fcb2,
                                              float* __restrict__ out) {
    __shared__ float s[256];
    int g   = blockIdx.x;
    int tid = threadIdx.x;
    int start = lower_bound(batch, N_NODES, g);
    int end   = lower_bound(batch, N_NODES, g + 1);
    int col = tid & 7;
    float local = 0.f;
    for (int n = start + (tid >> 3); n < end; n += 32)
        local += y2[(size_t)n * C2 + col];
    s[tid] = local;
    __syncthreads();
    for (int off = 128; off >= 8; off >>= 1) {
        if (tid < off) s[tid] += s[tid + off];
        __syncthreads();
    }
    if (tid == 0) {
        float cnt = fmaxf((float)(end - start), 1.f);
        float z[C2 + GDIM];
        for (int c = 0; c < C2; ++c) z[c] = s[c] / cnt;
        for (int c = 0; c < GDIM; ++c) z[C2 + c] = gfeat[g * GDIM + c];
        float acc2 = fcb2[0];
        for (int j = 0; j < 16; ++j) {
            float acc = fcb1[j];
            for (int c = 0; c < C2 + GDIM; ++c) acc += z[c] * fcW1[c * 16 + j];
            acc2 += lrelu(acc) * fcW2[j];
        }
        out[g] = lrelu(acc2);
    }
}

extern "C" void kernel_launch(void* const* d_in, const int* in_sizes, int n_in,
                              void* d_out, int out_size, void* d_ws, size_t ws_size,
                              hipStream_t stream) {
    const float* x     = (const float*)d_in[0];
    const int*   ei    = (const int*)d_in[1];
    const int*   batch = (const int*)d_in[2];
    const float* gfeat = (const float*)d_in[3];
    const float* W1    = (const float*)d_in[4];
    const float* b1    = (const float*)d_in[5];
    const float* W2    = (const float*)d_in[6];
    const float* b2    = (const float*)d_in[7];
    const float* fcW1  = (const float*)d_in[8];
    const float* fcb1  = (const float*)d_in[9];
    const float* fcW2  = (const float*)d_in[10];
    const float* fcb2  = (const float*)d_in[11];
    const int* src = ei;
    const int* dst = ei + N_EDGES;

    char* ws = (char*)d_ws;
    size_t off = 0;
    auto alloc = [&](size_t bytes) -> void* {
        void* p = ws + off;
        off = (off + bytes + 255) & ~(size_t)255;
        return p;
    };
    int*   cnt    = (int*)  alloc((size_t)NREP * N_NODES * 4);   // replicas -> ofs
    int*   deg    = (int*)  alloc((size_t)N_NODES * 4);
    float* dinv   = (float*)alloc((size_t)N_NODES * 4);
    int*   rowptr = (int*)  alloc((size_t)N_NODES * 4);
    int*   bsum   = (int*)  alloc(512 * 4);
    int*   bsumx  = (int*)  alloc(512 * 4);
    int*   rnk    = (int*)  alloc((size_t)N_EDGES * 4);
    int*   eidx   = (int*)  alloc((size_t)N_EDGES * 4);
    unsigned short* hs1 = (unsigned short*)alloc((size_t)N_NODES * HID * 2);
    float* hs2    = (float*)alloc((size_t)N_NODES * C2 * 4);
    float* y2     = (float*)alloc((size_t)N_NODES * C2 * 4);

    hipMemsetAsync(cnt, 0, (size_t)NREP * N_NODES * 4, stream);

    k_rank <<<(N_EDGES / 4 + 255) / 256, 256, 0, stream>>>(dst, cnt, rnk);
    k_scan1<<<NB_SCAN, 256, 0, stream>>>(cnt, deg, rowptr, bsum, dinv);
    k_scan2<<<1, 512, 0, stream>>>(bsum, bsumx);
    k_ofs  <<<NB_SCAN, 256, 0, stream>>>(cnt, rowptr, bsumx);
    k_place<<<(N_EDGES / 4 + 255) / 256, 256, 0, stream>>>(src, dst, rnk, cnt, eidx);

    k_gemm1<<<N_NODES / 32, 256, 0, stream>>>(x, W1, dinv, hs1);
    k_agg1 <<<N_NODES / 16, 256, 0, stream>>>(rowptr, bsumx, deg, eidx, hs1, dinv, b1, W2, hs2);
    k_agg2 <<<N_NODES / 16, 256, 0, stream>>>(rowptr, bsumx, deg, eidx, hs2, dinv, b2, y2);
    k_pool <<<NG, 256, 0, stream>>>(y2, batch, gfeat, fcW1, fcb1, fcW2, fcb2, (float*)d_out);
}

// Round 14
// 260.219 us; speedup vs baseline: 1.4214x; 1.0021x over previous
//
#include <hip/hip_runtime.h>

constexpr int N_NODES = 100000;
constexpr int N_EDGES = 1600000;
constexpr int IN_DIM  = 128;
constexpr int HID     = 64;
constexpr int C2      = 8;
constexpr int GDIM    = 24;
constexpr int NG      = 64;
constexpr int NREP    = 8;
constexpr float SLOPE = 0.01f;
constexpr int NB_SCAN = (N_NODES + 255) / 256;          // 391
constexpr int RANK_BLOCKS  = (N_EDGES / 4 + 255) / 256; // 1563
constexpr int GEMMF_BLOCKS = N_NODES / 16;              // 6250 (16 nodes/block)
constexpr int PLACE_BLOCKS = RANK_BLOCKS;               // 1563
constexpr int SCALE_BLOCKS = N_NODES * HID / 8 / 256;   // 3125 (8 f32/thread)

__device__ __forceinline__ float lrelu(float v) { return v > 0.f ? v : SLOPE * v; }

__device__ __forceinline__ float bflo(unsigned int u) { return __uint_as_float(u << 16); }
__device__ __forceinline__ float bfhi(unsigned int u) { return __uint_as_float(u & 0xffff0000u); }
__device__ __forceinline__ unsigned int f2bf_u(float f) {
    unsigned int i = __float_as_uint(f);
    return (i + 0x7fffu + ((i >> 16) & 1u)) >> 16;   // RNE, low 16 bits valid
}

// ---- fused front: rank blocks (atomics, latency-bound) ∥ gemm1 blocks (VALU) ----
// gemm writes UNSCALED f32 raw (dinv not yet available); scaled+rounded in k_mid.
__global__ __launch_bounds__(256) void k_front(const float* __restrict__ x,
                                               const float* __restrict__ W1,
                                               const int* __restrict__ dst,
                                               int* __restrict__ cnt,
                                               int* __restrict__ rnk,
                                               float* __restrict__ raw) {
    __shared__ float sW[IN_DIM * HID];   // 32 KiB
    __shared__ float sX[16][IN_DIM];     // 8 KiB  -> 40 KiB total, 4 blocks/CU
    if (blockIdx.x < RANK_BLOCKS) {
        int t = blockIdx.x * 256 + threadIdx.x;
        int* c = cnt + (size_t)(blockIdx.x & (NREP - 1)) * N_NODES;
        if (t < N_EDGES / 4) {
            int4 d = ((const int4*)dst)[t];
            int4 r;
            r.x = atomicAdd(&c[d.x], 1);
            r.y = atomicAdd(&c[d.y], 1);
            r.z = atomicAdd(&c[d.z], 1);
            r.w = atomicAdd(&c[d.w], 1);
            ((int4*)rnk)[t] = r;
        }
        return;
    }
    int node0 = (blockIdx.x - RANK_BLOCKS) * 16;     // 6250 * 16 == 100000
    for (int t = threadIdx.x; t < IN_DIM * HID / 4; t += 256)
        ((float4*)sW)[t] = ((const float4*)W1)[t];
    for (int t = threadIdx.x; t < 16 * IN_DIM / 4; t += 256) {
        int r = t >> 5, c4 = t & 31;
        ((float4*)&sX[r][0])[c4] = ((const float4*)(x + (size_t)(node0 + r) * IN_DIM))[c4];
    }
    __syncthreads();
    int col = threadIdx.x & 63;
    int nb  = (threadIdx.x >> 6) * 4;    // 4 nodes per wave
    float acc[4] = {0.f, 0.f, 0.f, 0.f};
    for (int k4 = 0; k4 < IN_DIM; k4 += 4) {
        float w0 = sW[(k4 + 0) * HID + col];
        float w1 = sW[(k4 + 1) * HID + col];
        float w2 = sW[(k4 + 2) * HID + col];
        float w3 = sW[(k4 + 3) * HID + col];
#pragma unroll
        for (int j = 0; j < 4; ++j) {
            float4 xv = *((const float4*)&sX[nb + j][k4]);
            acc[j] += xv.x * w0 + xv.y * w1 + xv.z * w2 + xv.w * w3;
        }
    }
#pragma unroll
    for (int j = 0; j < 4; ++j)
        raw[(size_t)(node0 + nb + j) * HID + col] = acc[j];
}

// ---- scan1: total deg = sum of replicas; dinv; block-local exclusive scan ----
__global__ void k_scan1(const int* __restrict__ cnt, int* __restrict__ deg,
                        int* __restrict__ rowptr, int* __restrict__ bsum,
                        float* __restrict__ dinv) {
    __shared__ int s[256];
    int tid = threadIdx.x;
    int i = blockIdx.x * 256 + tid;
    int v = 0;
    if (i < N_NODES) {
#pragma unroll
        for (int r = 0; r < NREP; ++r) v += cnt[(size_t)r * N_NODES + i];
        deg[i] = v;
        dinv[i] = rsqrtf((float)(v + 1));
    }
    s[tid] = v;
    __syncthreads();
    for (int off = 1; off < 256; off <<= 1) {
        int t = (tid >= off) ? s[tid - off] : 0;
        __syncthreads();
        s[tid] += t;
        __syncthreads();
    }
    if (i < N_NODES) rowptr[i] = s[tid] - v;   // block-local exclusive
    if (tid == 255) bsum[blockIdx.x] = s[255];
}

// ---- scan2: exclusive scan of block sums ----
__global__ void k_scan2(const int* __restrict__ bsum, int* __restrict__ bsumx) {
    __shared__ int s[512];
    int tid = threadIdx.x;
    int v = (tid < NB_SCAN) ? bsum[tid] : 0;
    s[tid] = v;
    __syncthreads();
    for (int off = 1; off < 512; off <<= 1) {
        int t = (tid >= off) ? s[tid - off] : 0;
        __syncthreads();
        s[tid] += t;
        __syncthreads();
    }
    if (tid < NB_SCAN) bsumx[tid] = s[tid] - v;
}

// ---- ofs: overwrite cnt[r][i] with global slot base for (replica r, node i) ----
__global__ void k_ofs(int* __restrict__ cnt, const int* __restrict__ rowptr,
                      const int* __restrict__ bsumx) {
    int i = blockIdx.x * 256 + threadIdx.x;
    if (i < N_NODES) {
        int g = rowptr[i] + bsumx[i >> 8];
#pragma unroll
        for (int r = 0; r < NREP; ++r) {
            int c = cnt[(size_t)r * N_NODES + i];
            cnt[(size_t)r * N_NODES + i] = g;
            g += c;
        }
    }
}

// ---- fused mid: place (scatter) ∥ scale (hs1 = bf16(raw*dinv), single rounding) ----
__global__ __launch_bounds__(256) void k_mid(const int* __restrict__ src,
                                             const int* __restrict__ dst,
                                             const int* __restrict__ rnk,
                                             const int* __restrict__ cnt,
                                             int* __restrict__ eidx,
                                             const float* __restrict__ raw,
                                             const float* __restrict__ dinv,
                                             unsigned short* __restrict__ hs1) {
    if (blockIdx.x < PLACE_BLOCKS) {
        int t = blockIdx.x * 256 + threadIdx.x;
        const int* ofs = cnt + (size_t)(blockIdx.x & (NREP - 1)) * N_NODES;
        if (t < N_EDGES / 4) {
            int4 d = ((const int4*)dst)[t];
            int4 r = ((const int4*)rnk)[t];
            int4 s = ((const int4*)src)[t];
            eidx[ofs[d.x] + r.x] = s.x;
            eidx[ofs[d.y] + r.y] = s.y;
            eidx[ofs[d.z] + r.z] = s.z;
            eidx[ofs[d.w] + r.w] = s.w;
        }
        return;
    }
    int t = (blockIdx.x - PLACE_BLOCKS) * 256 + threadIdx.x;   // < 800000 exactly
    int node = t >> 3;                      // 8 f32 per thread, 64 per row
    float di = dinv[node];
    float4 a = ((const float4*)raw)[2 * t];
    float4 b = ((const float4*)raw)[2 * t + 1];
    uint4 o;
    o.x = f2bf_u(a.x * di) | (f2bf_u(a.y * di) << 16);
    o.y = f2bf_u(a.z * di) | (f2bf_u(a.w * di) << 16);
    o.z = f2bf_u(b.x * di) | (f2bf_u(b.y * di) << 16);
    o.w = f2bf_u(b.z * di) | (f2bf_u(b.w * di) << 16);
    ((uint4*)hs1)[t] = o;
}

// ---- layer-1 aggregate + epilogue + fused layer-2 GEMM: 8 nodes per wave ----
__global__ __launch_bounds__(256) void k_agg1(const int* __restrict__ rowptr,
                                              const int* __restrict__ bsumx,
                                              const int* __restrict__ deg,
                                              const int* __restrict__ eidx,
                                              const unsigned short* __restrict__ hs1,
                                              const float* __restrict__ dinv,
                                              const float* __restrict__ b1,
                                              const float* __restrict__ W2,
                                              float* __restrict__ hs2) {
    int lane = threadIdx.x & 63;
    int q    = lane & 7;     // columns 8q..8q+7
    int slot = lane >> 3;    // 8 edge slots
    float w2f[8];
#pragma unroll
    for (int i = 0; i < 8; ++i) w2f[i] = W2[(8 * q + i) * C2 + slot];
    float4 bb0 = ((const float4*)b1)[2 * q];
    float4 bb1 = ((const float4*)b1)[2 * q + 1];
    float bv[8] = {bb0.x, bb0.y, bb0.z, bb0.w, bb1.x, bb1.y, bb1.z, bb1.w};
    int node_base = blockIdx.x * 32 + (threadIdx.x >> 6) * 8;   // 3125 * 32 == 100000

    for (int nn = 0; nn < 8; ++nn) {
        int node  = node_base + nn;
        int start = rowptr[node] + bsumx[node >> 8];
        int cnt   = deg[node];
        uint4 hv = ((const uint4*)(hs1 + (size_t)node * HID))[q];
        float acc[8] = {0.f, 0.f, 0.f, 0.f, 0.f, 0.f, 0.f, 0.f};
        for (int base = 0; base < cnt; base += 64) {
            int idx = (base + lane < cnt) ? eidx[start + base + lane] : 0;
            int lim = min(64, cnt - base);       // uniform across wave
            int trips = (lim + 15) >> 4;         // uniform: 1..4
            for (int t = 0; t < trips; ++t) {
                int k0 = slot + t * 16;
                int k1 = k0 + 8;
                int s0 = __shfl(idx, k0);
                int s1 = __shfl(idx, k1 & 63);
                uint4 v0 = ((const uint4*)(hs1 + (size_t)s0 * HID))[q];
                uint4 v1 = ((const uint4*)(hs1 + (size_t)s1 * HID))[q];
                if (k0 >= lim) { v0.x = 0; v0.y = 0; v0.z = 0; v0.w = 0; }
                if (k1 >= lim) { v1.x = 0; v1.y = 0; v1.z = 0; v1.w = 0; }
                acc[0] += bflo(v0.x); acc[1] += bfhi(v0.x);
                acc[2] += bflo(v0.y); acc[3] += bfhi(v0.y);
                acc[4] += bflo(v0.z); acc[5] += bfhi(v0.z);
                acc[6] += bflo(v0.w); acc[7] += bfhi(v0.w);
                acc[0] += bflo(v1.x); acc[1] += bfhi(v1.x);
                acc[2] += bflo(v1.y); acc[3] += bfhi(v1.y);
                acc[4] += bflo(v1.z); acc[5] += bfhi(v1.z);
                acc[6] += bflo(v1.w); acc[7] += bfhi(v1.w);
            }
        }
#pragma unroll
        for (int m = 8; m < 64; m <<= 1)
#pragma unroll
            for (int i = 0; i < 8; ++i) acc[i] += __shfl_xor(acc[i], m);
        float self[8] = {bflo(hv.x), bfhi(hv.x), bflo(hv.y), bfhi(hv.y),
                         bflo(hv.z), bfhi(hv.z), bflo(hv.w), bfhi(hv.w)};
        float di = dinv[node];
        float p = 0.f;
#pragma unroll
        for (int i = 0; i < 8; ++i) {
            float y = lrelu(di * (acc[i] + self[i]) + bv[i]);
            p += y * w2f[i];
        }
#pragma unroll
        for (int m = 1; m < 8; m <<= 1) p += __shfl_xor(p, m);
        if (q == 0) hs2[(size_t)node * C2 + slot] = p * di;
    }
}

// ---- layer-2 aggregate + epilogue: 8 nodes per wave ----
__global__ __launch_bounds__(256) void k_agg2(const int* __restrict__ rowptr,
                                              const int* __restrict__ bsumx,
                                              const int* __restrict__ deg,
                                              const int* __restrict__ eidx,
                                              const float* __restrict__ hs2,
                                              const float* __restrict__ dinv,
                                              const float* __restrict__ b2,
                                              float* __restrict__ y2) {
    int lane = threadIdx.x & 63;
    int q    = lane & 1;
    int slot = lane >> 1;    // 32 slots
    int node_base = blockIdx.x * 32 + (threadIdx.x >> 6) * 8;   // 3125 * 32 == 100000

    for (int nn = 0; nn < 8; ++nn) {
        int node  = node_base + nn;
        int start = rowptr[node] + bsumx[node >> 8];
        int cnt   = deg[node];
        float4 acc = make_float4(0.f, 0.f, 0.f, 0.f);
        for (int base = 0; base < cnt; base += 64) {
            int idx = (base + lane < cnt) ? eidx[start + base + lane] : 0;
            int lim = min(64, cnt - base);       // uniform
            int s0 = __shfl(idx, slot);
            int s1 = __shfl(idx, slot + 32);
            float4 v0 = ((const float4*)(hs2 + (size_t)s0 * C2))[q];
            float4 v1 = ((const float4*)(hs2 + (size_t)s1 * C2))[q];
            if (slot >= lim)      { v0.x = 0.f; v0.y = 0.f; v0.z = 0.f; v0.w = 0.f; }
            if (slot + 32 >= lim) { v1.x = 0.f; v1.y = 0.f; v1.z = 0.f; v1.w = 0.f; }
            acc.x += v0.x + v1.x; acc.y += v0.y + v1.y;
            acc.z += v0.z + v1.z; acc.w += v0.w + v1.w;
        }
        for (int m = 2; m < 64; m <<= 1) {
            acc.x += __shfl_xor(acc.x, m); acc.y += __shfl_xor(acc.y, m);
            acc.z += __shfl_xor(acc.z, m); acc.w += __shfl_xor(acc.w, m);
        }
        if (slot == 0) {
            float4 h = ((const float4*)(hs2 + (size_t)node * C2))[q];
            float di = dinv[node];
            const float* bb = b2 + q * 4;
            float4 r;
            r.x = lrelu(di * (acc.x + h.x) + bb[0]);
            r.y = lrelu(di * (acc.y + h.y) + bb[1]);
            r.z = lrelu(di * (acc.z + h.z) + bb[2]);
            r.w = lrelu(di * (acc.w + h.w) + bb[3]);
            ((float4*)(y2 + (size_t)node * C2))[q] = r;
        }
    }
}

__device__ __forceinline__ int lower_bound(const int* __restrict__ b, int n, int v) {
    int lo = 0, hi = n;
    while (lo < hi) {
        int m = (lo + hi) >> 1;
        if (b[m] < v) lo = m + 1; else hi = m;
    }
    return lo;
}

// ---- pool + MLP: one block per graph, zero atomics ----
__global__ __launch_bounds__(256) void k_pool(const float* __restrict__ y2,
                                              const int* __restrict__ batch,
                                              const float* __restrict__ gfeat,
                                              const float* __restrict__ fcW1,
                                              const float* __restrict__ fcb1,
                                              const float* __restrict__ fcW2,
                                              const float* __restrict__ fcb2,
                                              float* __restrict__ out) {
    __shared__ float s[256];
    int g   = blockIdx.x;
    int tid = threadIdx.x;
    int start = lower_bound(batch, N_NODES, g);
    int end   = lower_bound(batch, N_NODES, g + 1);
    int col = tid & 7;
    float local = 0.f;
    for (int n = start + (tid >> 3); n < end; n += 32)
        local += y2[(size_t)n * C2 + col];
    s[tid] = local;
    __syncthreads();
    for (int off = 128; off >= 8; off >>= 1) {
        if (tid < off) s[tid] += s[tid + off];
        __syncthreads();
    }
    if (tid == 0) {
        float cnt = fmaxf((float)(end - start), 1.f);
        float z[C2 + GDIM];
        for (int c = 0; c < C2; ++c) z[c] = s[c] / cnt;
        for (int c = 0; c < GDIM; ++c) z[C2 + c] = gfeat[g * GDIM + c];
        float acc2 = fcb2[0];
        for (int j = 0; j < 16; ++j) {
            float acc = fcb1[j];
            for (int c = 0; c < C2 + GDIM; ++c) acc += z[c] * fcW1[c * 16 + j];
            acc2 += lrelu(acc) * fcW2[j];
        }
        out[g] = lrelu(acc2);
    }
}

extern "C" void kernel_launch(void* const* d_in, const int* in_sizes, int n_in,
                              void* d_out, int out_size, void* d_ws, size_t ws_size,
                              hipStream_t stream) {
    const float* x     = (const float*)d_in[0];
    const int*   ei    = (const int*)d_in[1];
    const int*   batch = (const int*)d_in[2];
    const float* gfeat = (const float*)d_in[3];
    const float* W1    = (const float*)d_in[4];
    const float* b1    = (const float*)d_in[5];
    const float* W2    = (const float*)d_in[6];
    const float* b2    = (const float*)d_in[7];
    const float* fcW1  = (const float*)d_in[8];
    const float* fcb1  = (const float*)d_in[9];
    const float* fcW2  = (const float*)d_in[10];
    const float* fcb2  = (const float*)d_in[11];
    const int* src = ei;
    const int* dst = ei + N_EDGES;

    char* ws = (char*)d_ws;
    size_t off = 0;
    auto alloc = [&](size_t bytes) -> void* {
        void* p = ws + off;
        off = (off + bytes + 255) & ~(size_t)255;
        return p;
    };
    int*   cnt    = (int*)  alloc((size_t)NREP * N_NODES * 4);   // replicas -> ofs
    int*   deg    = (int*)  alloc((size_t)N_NODES * 4);
    float* dinv   = (float*)alloc((size_t)N_NODES * 4);
    int*   rowptr = (int*)  alloc((size_t)N_NODES * 4);
    int*   bsum   = (int*)  alloc(512 * 4);
    int*   bsumx  = (int*)  alloc(512 * 4);
    int*   rnk    = (int*)  alloc((size_t)N_EDGES * 4);
    int*   eidx   = (int*)  alloc((size_t)N_EDGES * 4);
    unsigned short* hs1 = (unsigned short*)alloc((size_t)N_NODES * HID * 2);
    float* raw    = (float*)alloc((size_t)N_NODES * HID * 4);    // f32, dead after k_mid
    // hs2 / y2 alias raw (alive only after k_mid)
    float* hs2 = raw;
    float* y2  = raw + (size_t)N_NODES * C2;

    hipMemsetAsync(cnt, 0, (size_t)NREP * N_NODES * 4, stream);

    k_front<<<RANK_BLOCKS + GEMMF_BLOCKS, 256, 0, stream>>>(x, W1, dst, cnt, rnk, raw);
    k_scan1<<<NB_SCAN, 256, 0, stream>>>(cnt, deg, rowptr, bsum, dinv);
    k_scan2<<<1, 512, 0, stream>>>(bsum, bsumx);
    k_ofs  <<<NB_SCAN, 256, 0, stream>>>(cnt, rowptr, bsumx);
    k_mid  <<<PLACE_BLOCKS + SCALE_BLOCKS, 256, 0, stream>>>(src, dst, rnk, cnt, eidx,
                                                             raw, dinv, hs1);
    k_agg1 <<<N_NODES / 32, 256, 0, stream>>>(rowptr, bsumx, deg, eidx, hs1, dinv, b1, W2, hs2);
    k_agg2 <<<N_NODES / 32, 256, 0, stream>>>(rowptr, bsumx, deg, eidx, hs2, dinv, b2, y2);
    k_pool <<<NG, 256, 0, stream>>>(y2, batch, gfeat, fcW1, fcb1, fcW2, fcb2, (float*)d_out);
}